// Round 5
// baseline (535.889 us; speedup 1.0000x reference)
//
#include <hip/hip_runtime.h>
#include <stdint.h>

#define IN_F 4096
#define OUT_F 14336
#define QBLK 64

__device__ __constant__ float NF4_CODE_C[16] = {
    -1.0f, -0.6961928009986877f, -0.5250730514526367f, -0.39491748809814453f,
    -0.28444138169288635f, -0.18477343022823334f, -0.09105003625154495f, 0.0f,
    0.07958029955625534f, 0.16093020141124725f, 0.24611230194568634f,
    0.33791524171829224f, 0.44070982933044434f, 0.5626170039176941f,
    0.8333911895751953f, 1.0f};

typedef __attribute__((ext_vector_type(8))) short short8;   // 8 bf16 (4 VGPRs)
typedef __attribute__((ext_vector_type(4))) float f32x4;    // MFMA acc

__device__ __forceinline__ unsigned short f32_to_bf16_rne(float f) {
    union { float f; uint32_t u; } a; a.f = f;
    uint32_t u = a.u;
    uint32_t r = u + 0x7fffu + ((u >> 16) & 1u);
    return (unsigned short)(r >> 16);
}

// ---------------- Pass 1a: dequant W -> bf16 [N][K]
__global__ void dequant_w_kernel(const int* __restrict__ w,
                                 const float* __restrict__ absmax,
                                 unsigned short* __restrict__ W,
                                 long long n8) {
    long long i = (long long)blockIdx.x * blockDim.x + threadIdx.x;
    long long stride = (long long)gridDim.x * blockDim.x;
    for (; i < n8; i += stride) {
        const int4* p = (const int4*)(w + i * 8);
        int4 v0 = p[0], v1 = p[1];
        float s = absmax[i >> 3];
        union { unsigned short u[8]; float4 v; } out;
        out.u[0] = f32_to_bf16_rne(NF4_CODE_C[v0.x] * s);
        out.u[1] = f32_to_bf16_rne(NF4_CODE_C[v0.y] * s);
        out.u[2] = f32_to_bf16_rne(NF4_CODE_C[v0.z] * s);
        out.u[3] = f32_to_bf16_rne(NF4_CODE_C[v0.w] * s);
        out.u[4] = f32_to_bf16_rne(NF4_CODE_C[v1.x] * s);
        out.u[5] = f32_to_bf16_rne(NF4_CODE_C[v1.y] * s);
        out.u[6] = f32_to_bf16_rne(NF4_CODE_C[v1.z] * s);
        out.u[7] = f32_to_bf16_rne(NF4_CODE_C[v1.w] * s);
        *(float4*)(W + i * 8) = out.v;
    }
}

// ---------------- Pass 1b: x fp32 -> bf16
__global__ void cvt_x_kernel(const float* __restrict__ x,
                             unsigned short* __restrict__ xb,
                             long long n8) {
    long long i = (long long)blockIdx.x * blockDim.x + threadIdx.x;
    long long stride = (long long)gridDim.x * blockDim.x;
    for (; i < n8; i += stride) {
        const float4* p = (const float4*)(x + i * 8);
        float4 a = p[0], b = p[1];
        union { unsigned short u[8]; float4 v; } out;
        out.u[0] = f32_to_bf16_rne(a.x);
        out.u[1] = f32_to_bf16_rne(a.y);
        out.u[2] = f32_to_bf16_rne(a.z);
        out.u[3] = f32_to_bf16_rne(a.w);
        out.u[4] = f32_to_bf16_rne(b.x);
        out.u[5] = f32_to_bf16_rne(b.y);
        out.u[6] = f32_to_bf16_rne(b.z);
        out.u[7] = f32_to_bf16_rne(b.w);
        *(float4*)(xb + i * 8) = out.v;
    }
}

// ---------------- Pass 2: two-barrier 8-phase-style pipelined bf16 GEMM (B^T)
// 256x256 tile, BK=64, 2 LDS buffers (128 KiB), 8 waves (2M x 4N), wave tile
// 128x64. Per phase: [ds_reads; 2 stage loads] BAR | pure 16-MFMA region | BAR.
// vmcnt(4) per phase end (every staged chunk lands 2 phase-ends after issue,
// first read >=1 phase later -- ledger identical to r4, proven correct).
__device__ __forceinline__ void llds16(const unsigned short* g, unsigned short* l) {
    __builtin_amdgcn_global_load_lds(
        (const __attribute__((address_space(1))) unsigned int*)g,
        (__attribute__((address_space(3))) unsigned int*)l,
        16, 0, 0);
}

#define GK 4096
#define GN 14336

__global__ void __launch_bounds__(512, 2)
gemm_2bar_bf16(const unsigned short* __restrict__ A,  // [M][4096] bf16 bits
               const unsigned short* __restrict__ B,  // [14336][4096] bf16 bits
               const float* __restrict__ bias,
               float* __restrict__ C, int Mtiles) {
    __shared__ unsigned short lds[65536];
    const int tid  = threadIdx.x;
    const int lane = tid & 63;
    const int wv   = tid >> 6;        // wave 0..7
    const int wr   = wv >> 2;         // M half
    const int wc   = wv & 3;          // N quarter

    // T1: bijective XCD swizzle (m204)
    const int nwg = gridDim.x;
    const int q = nwg >> 3, r = nwg & 7;
    const int xcd = blockIdx.x & 7, loc = blockIdx.x >> 3;
    const int s = (xcd < r ? xcd * (q + 1) : r * (q + 1) + (xcd - r) * q) + loc;
    const int tm = s % Mtiles;
    const int tn = s / Mtiles;
    const int brow = tm * 256;
    const int bcol = tn * 256;

    f32x4 acc[8][4] = {};

    // staging: lane l covers 8 rows x 8 chunk-slots; LDS dest linear,
    // global 16B-chunk pre-swizzled (T2, rule #21 both-sides)
    const int l8 = lane >> 3, l7 = lane & 7;
    const int gch = (l7 ^ (l8 & 7)) * 8;
    const unsigned short* pA = A + (size_t)(brow + wv * 8 + l8) * GK + gch;
    const unsigned short* pB = B + (size_t)(bcol + (wv >> 2) * 64 + (wv & 3) * 8 + l8) * GK + gch;
    const int ldsA = wv * 512;
    const int ldsB = 16384 + (wv >> 2) * 4096 + (wv & 3) * 512;

    // read offsets: slot = (kgrp + 4*kk) ^ (row&7)
    const int sl0 = (((lane >> 4)    ) ^ l7) * 8;
    const int sl1 = (((lane >> 4) + 4) ^ l7) * 8;
    const int ab = (wr * 128 + (lane & 15)) * 64;
    const int bb = 16384 + (wc * 64 + (lane & 15)) * 64;

#define ST_A(c, T, O)    llds16(pA + (size_t)(c) * 64 * GK + (size_t)(T) * 64, &lds[(O) + (c) * 4096 + ldsA])
#define ST_B(P, qq, T, O) llds16(pB + (size_t)((P) * 128 + (qq) * 32) * GK + (size_t)(T) * 64, &lds[(O) + (P) * 8192 + (qq) * 2048 + ldsB])

#define RD_A(af, qm, O) do { _Pragma("unroll")                                  \
    for (int rt = 0; rt < 4; ++rt) {                                            \
        af[rt][0] = *(const short8*)&lds[(O) + ab + (qm) * 4096 + rt * 1024 + sl0]; \
        af[rt][1] = *(const short8*)&lds[(O) + ab + (qm) * 4096 + rt * 1024 + sl1]; \
    } } while (0)
#define RD_B(bq, qn, O) do { _Pragma("unroll")                                  \
    for (int nt = 0; nt < 2; ++nt) {                                            \
        bq[nt][0] = *(const short8*)&lds[(O) + bb + (qn) * 2048 + nt * 1024 + sl0]; \
        bq[nt][1] = *(const short8*)&lds[(O) + bb + (qn) * 2048 + nt * 1024 + sl1]; \
    } } while (0)
#define MM(af, bq, i0, n0) do {                                                 \
    __builtin_amdgcn_s_setprio(1);                                              \
    _Pragma("unroll") for (int rt = 0; rt < 4; ++rt)                            \
    _Pragma("unroll") for (int nt = 0; nt < 2; ++nt)                            \
    _Pragma("unroll") for (int kk = 0; kk < 2; ++kk)                            \
        acc[(i0) + rt][(n0) + nt] = __builtin_amdgcn_mfma_f32_16x16x32_bf16(    \
            af[rt][kk], bq[nt][kk], acc[(i0) + rt][(n0) + nt], 0, 0, 0);        \
    __builtin_amdgcn_s_setprio(0);                                              \
} while (0)

#define VMW(N) asm volatile("s_waitcnt vmcnt(" #N ")" ::: "memory")
#define BAR()  __builtin_amdgcn_s_barrier()
#define SBAR() __builtin_amdgcn_sched_barrier(0)

// Phase = [reads first, then stages] BAR | pure MFMA | vmcnt BAR.
// Stage order A0A2 / B00B10 / B01B11 / A1A3; reads af0+bq0 @ph1, bq1 @ph2,
// af1 @ph3. All deadlines hold under uniform vmcnt(4) (2-phase-end landing).
#define TILE_BODY(O, NO, T) do {                                                \
    short8 af0[4][2], af1[4][2], bq0[2][2], bq1[2][2];                          \
    /* ph1 */                                                                   \
    RD_A(af0, 0, O); RD_B(bq0, 0, O);                                           \
    ST_A(0, T, NO); ST_A(2, T, NO);                                             \
    BAR(); SBAR();                                                              \
    MM(af0, bq0, 0, 0);                                                         \
    SBAR(); VMW(4); BAR();                                                      \
    /* ph2 */                                                                   \
    RD_B(bq1, 1, O);                                                            \
    ST_B(0, 0, T, NO); ST_B(1, 0, T, NO);                                       \
    BAR(); SBAR();                                                              \
    MM(af0, bq1, 0, 2);                                                         \
    SBAR(); VMW(4); BAR();                                                      \
    /* ph3 */                                                                   \
    RD_A(af1, 1, O);                                                            \
    ST_B(0, 1, T, NO); ST_B(1, 1, T, NO);                                       \
    BAR(); SBAR();                                                              \
    MM(af1, bq0, 4, 0);                                                         \
    SBAR(); VMW(4); BAR();                                                      \
    /* ph4 */                                                                   \
    ST_A(1, T, NO); ST_A(3, T, NO);                                             \
    BAR(); SBAR();                                                              \
    MM(af1, bq1, 4, 2);                                                         \
    SBAR(); VMW(4); BAR();                                                      \
} while (0)

    // prologue: stage tile 0 into buf0 (deadline order), land first 4 chunks
    ST_A(0, 0, 0); ST_A(2, 0, 0);
    ST_B(0, 0, 0, 0); ST_B(1, 0, 0, 0);
    ST_B(0, 1, 0, 0); ST_B(1, 1, 0, 0);
    ST_A(1, 0, 0); ST_A(3, 0, 0);
    VMW(4); BAR();

    // main: NT=64 K-tiles; tiles 0..62 stage their successor
    for (int t = 0; t < 62; t += 2) {
        TILE_BODY(0,     32768, t + 1);
        TILE_BODY(32768, 0,     t + 2);
    }
    TILE_BODY(0, 32768, 63);   // tile 62, stages tile 63

    { // tail: tile 63 (buf1) -- all data landed after vmcnt(0)+BAR
        short8 af0[4][2], af1[4][2], bq0[2][2], bq1[2][2];
        VMW(0); BAR();
        RD_A(af0, 0, 32768); RD_B(bq0, 0, 32768);
        RD_B(bq1, 1, 32768); RD_A(af1, 1, 32768);
        MM(af0, bq0, 0, 0);
        MM(af0, bq1, 0, 2);
        MM(af1, bq0, 4, 0);
        MM(af1, bq1, 4, 2);
    }

#undef TILE_BODY
#undef VMW
#undef BAR
#undef SBAR
#undef MM
#undef RD_A
#undef RD_B
#undef ST_A
#undef ST_B

    // epilogue: D col = lane&15, row = (lane>>4)*4 + j
    #pragma unroll
    for (int n = 0; n < 4; ++n) {
        const int col = bcol + wc * 64 + n * 16 + (lane & 15);
        const float bv = bias[col];
        #pragma unroll
        for (int i = 0; i < 8; ++i) {
            #pragma unroll
            for (int j = 0; j < 4; ++j) {
                const int row = brow + wr * 128 + i * 16 + (lane >> 4) * 4 + j;
                C[(size_t)row * GN + col] = acc[i][n][j] + bv;
            }
        }
    }
}

// ---------------- fallback: naive fused fp32
__global__ void naive_fused(const float* __restrict__ x, const int* __restrict__ w,
                            const float* __restrict__ am, const float* __restrict__ bias,
                            float* __restrict__ out, int M) {
    long long o = (long long)blockIdx.x * blockDim.x + threadIdx.x;
    if (o >= (long long)M * OUT_F) return;
    int m = (int)(o / OUT_F), n = (int)(o % OUT_F);
    const int* wr_ = w + (size_t)n * IN_F;
    const float* xr = x + (size_t)m * IN_F;
    const float* amr = am + (size_t)n * (IN_F / QBLK);
    float sum = 0.f;
    for (int k = 0; k < IN_F; ++k)
        sum += xr[k] * NF4_CODE_C[wr_[k]] * amr[k >> 6];
    out[o] = sum + bias[n];
}

extern "C" void kernel_launch(void* const* d_in, const int* in_sizes, int n_in,
                              void* d_out, int out_size, void* d_ws, size_t ws_size,
                              hipStream_t stream) {
    const float* x      = (const float*)d_in[0];
    const int*   w_idx  = (const int*)d_in[1];
    const float* absmax = (const float*)d_in[2];
    const float* bias   = (const float*)d_in[3];
    float* out = (float*)d_out;

    const int M = in_sizes[0] / IN_F;   // 4096
    const int N = OUT_F;                // 14336
    const int K = IN_F;                 // 4096

    const size_t needW = (size_t)N * K * 2;
    const size_t needX = (size_t)M * K * 2;
    if (ws_size >= needW + needX && (M % 256) == 0) {
        unsigned short* Wb = (unsigned short*)d_ws;
        unsigned short* Xb = (unsigned short*)((char*)d_ws + needW);

        long long n8w = (long long)N * K / 8;
        dequant_w_kernel<<<8192, 256, 0, stream>>>(w_idx, absmax, Wb, n8w);
        long long n8x = (long long)M * K / 8;
        cvt_x_kernel<<<4096, 256, 0, stream>>>(x, Xb, n8x);

        const int Mtiles = M / 256;
        dim3 grid(Mtiles * (N / 256));
        gemm_2bar_bf16<<<grid, 512, 0, stream>>>(Xb, Wb, bias, out, Mtiles);
    } else {
        long long total = (long long)M * OUT_F;
        int blocks = (int)((total + 255) / 256);
        naive_fused<<<blocks, 256, 0, stream>>>(x, w_idx, absmax, bias, out, M);
    }
}